// Round 5
// baseline (193.806 us; speedup 1.0000x reference)
//
#include <hip/hip_runtime.h>

// GAE: (B=8192, T=256, A=4, 1) fp32.
// g[t] = d[t] + c[t]*g[t+1], c = GAMMA*LMBDA*(1-term), g[T]=0
// adv = g, ret = g + v. d_out = [adv | ret] flat.
//
// Round-8 (occupancy + XCD-swizzle test):
//   BW ledger: 32 waves/CU -> 2.40 TB/s, 16 -> 2.36, 8 -> 2.17. Weak but
//   monotone concurrency response; everything else (NT stores, pipeline
//   depth, stream spread) measured null. FETCH is pinned at ~65.6 MB by an
//   L3 random-replacement equilibrium (192 MiB/iter footprint in 256 MiB
//   -> ~50% input hit) - not a lever. This round: restore 16 waves/CU
//   (1024 one-shot blocks = exactly 4/CU, zero tail) with the verified
//   2-seq prefetch pipeline, add XCD-bijective block swizzle so each XCD
//   reads a contiguous 512-sequence (2 MiB/array) slice. NT reverted
//   (measured exactly neutral).
//
// Per-wave phases (verified r1-r4):
//   A: coalesced float4 loads (thread=timestep), compute (d, cont-flag),
//      transpose-write into wave-private LDS slice (swizzled, <=2-way).
//   B: thread (tc,a) owns 16 steps; chunk composite + 4-round shuffle scan
//      + replay. Wave-local s_waitcnt lgkmcnt(0) instead of __syncthreads.
//   C: transpose-read g, coalesced float4 stores of adv and ret=g+v.

#define GAMMA 0.99f
#define LMBDA 0.95f

typedef float f32x4 __attribute__((ext_vector_type(4)));
typedef unsigned char u8;

constexpr float K0 = GAMMA * LMBDA;

__device__ __forceinline__ void issue_loads(
    const f32x4* __restrict__ R4, const f32x4* __restrict__ T4,
    const f32x4* __restrict__ V4, const f32x4* __restrict__ N4,
    int b, int lane, f32x4 r[4], f32x4 tm[4], f32x4 v[4], f32x4 nv[4])
{
#pragma unroll
    for (int q = 0; q < 4; ++q) {
        const int gi = b * 256 + 64 * q + lane;
        r[q]  = R4[gi];
        tm[q] = T4[gi];
        v[q]  = V4[gi];
        nv[q] = N4[gi];
    }
}

// Consume loaded regs: compute (d, cont-flag), transpose-write into LDS.
__device__ __forceinline__ void phaseA(
    float* __restrict__ D_, u8* __restrict__ C_, int lane,
    const f32x4 r[4], const f32x4 tm[4], const f32x4 nv[4], const f32x4 v[4])
{
#pragma unroll
    for (int q = 0; q < 4; ++q) {
        const int f    = 64 * q + lane;          // float4 index = timestep t
        const int s    = 255 - f;                // scan index (reversed time)
        const int row  = s & 15;
        const int col  = (4 * (s >> 4) + 4 * row) & 63;
        const int addr = row * 64 + col;         // 4-aligned

        f32x4 d4;
        d4.x = r[q].x + GAMMA * nv[q].x * (1.0f - tm[q].x) - v[q].x;
        d4.y = r[q].y + GAMMA * nv[q].y * (1.0f - tm[q].y) - v[q].y;
        d4.z = r[q].z + GAMMA * nv[q].z * (1.0f - tm[q].z) - v[q].z;
        d4.w = r[q].w + GAMMA * nv[q].w * (1.0f - tm[q].w) - v[q].w;
        const unsigned pk = (tm[q].x == 0.0f ? 0x00000001u : 0u)
                          | (tm[q].y == 0.0f ? 0x00000100u : 0u)
                          | (tm[q].z == 0.0f ? 0x00010000u : 0u)
                          | (tm[q].w == 0.0f ? 0x01000000u : 0u);
        *((f32x4*)&D_[addr])    = d4;
        *((unsigned*)&C_[addr]) = pk;
    }
}

// Wave scan over LDS slice + transposed coalesced stores.
__device__ __forceinline__ void scan_store(
    float* __restrict__ D_, const u8* __restrict__ C_,
    int lane, int b, const f32x4 v4[4],
    f32x4* __restrict__ adv4, f32x4* __restrict__ ret4)
{
    // Wave-local ordering: phase-A ds_writes complete before phase-B ds_reads.
    asm volatile("s_waitcnt lgkmcnt(0)" ::: "memory");

    const int tc = lane >> 2;    // time chunk 0..15
    const int a  = lane & 3;     // agent channel

    float d[16];
    unsigned mask = 0;           // bit j = continuation flag of step j
#pragma unroll
    for (int j = 0; j < 16; ++j) {
        const int col = (4 * tc + 4 * j + a) & 63;
        d[j] = D_[j * 64 + col];
        mask |= ((unsigned)C_[j * 64 + col]) << j;
    }

    // Local chunk composite: out = D + K * in.
    float D = d[0];
    float K = (mask & 1u) ? K0 : 0.0f;
#pragma unroll
    for (int j = 1; j < 16; ++j) {
        const float cj = ((mask >> j) & 1u) ? K0 : 0.0f;
        D = d[j] + cj * D;
        K = cj * K;
    }

    // Inclusive shuffle scan over tc (lane stride 4): 4 steps.
#pragma unroll
    for (int s2 = 1; s2 < 16; s2 <<= 1) {
        const float pD = __shfl_up(D, (unsigned)(4 * s2), 64);
        const float pK = __shfl_up(K, (unsigned)(4 * s2), 64);
        if (tc >= s2) { D = D + K * pD; K = K * pK; }
    }

    // Exclusive prefix = state entering this chunk.
    float x = __shfl_up(D, 4u, 64);
    if (tc == 0) x = 0.0f;

    // Replay chunk, write g back into D-buffer (d already in regs).
    float g = x;
#pragma unroll
    for (int j = 0; j < 16; ++j) {
        const float cj = ((mask >> j) & 1u) ? K0 : 0.0f;
        g = d[j] + cj * g;
        const int col = (4 * tc + 4 * j + a) & 63;
        D_[j * 64 + col] = g;
    }
    asm volatile("s_waitcnt lgkmcnt(0)" ::: "memory");

    // Transpose-read g, coalesced float4 stores.
#pragma unroll
    for (int q = 0; q < 4; ++q) {
        const int f   = 64 * q + lane;
        const int s   = 255 - f;
        const int row = s & 15;
        const int col = (4 * (s >> 4) + 4 * row) & 63;
        const f32x4 g4 = *((const f32x4*)&D_[row * 64 + col]);

        const int gi = b * 256 + f;
        adv4[gi] = g4;
        ret4[gi] = g4 + v4[q];
    }
    // Keep the following phase-A ds_writes ordered after this phase's reads.
    asm volatile("" ::: "memory");
}

__global__ __launch_bounds__(256, 4) void gae_scan_kernel(
    const float* __restrict__ reward,
    const float* __restrict__ terminated,
    const float* __restrict__ value,
    const float* __restrict__ next_value,
    float* __restrict__ adv_out,
    float* __restrict__ ret_out)
{
    __shared__ float bufD[4][16 * 64];           // 16 KB: d, then reused for g
    __shared__ u8    bufC[4][16 * 64];           //  4 KB: continuation flags

    const int w    = threadIdx.x >> 6;
    const int lane = threadIdx.x & 63;

    // XCD-bijective swizzle: 1024 blocks round-robin onto 8 XCDs; remap so
    // XCD k owns a contiguous 128-block (512-sequence, 2 MiB/array) slice.
    const int bid  = blockIdx.x;
    const int sbid = (bid & 7) * 128 + (bid >> 3);
    const int wv   = sbid * 4 + w;               // global wave id, 0..4095

    float* __restrict__ D_ = bufD[w];
    u8*    __restrict__ C_ = bufC[w];

    const f32x4* R4 = (const f32x4*)reward;
    const f32x4* T4 = (const f32x4*)terminated;
    const f32x4* V4 = (const f32x4*)value;
    const f32x4* N4 = (const f32x4*)next_value;
    f32x4* adv4 = (f32x4*)adv_out;
    f32x4* ret4 = (f32x4*)ret_out;

    const int b0 = wv;           // first sequence
    const int b1 = wv + 4096;    // second sequence (pipelined)

    f32x4 r0[4], t0[4], v0[4], n0[4];
    issue_loads(R4, T4, V4, N4, b0, lane, r0, t0, v0, n0);
    phaseA(D_, C_, lane, r0, t0, n0, v0);

    f32x4 r1[4], t1[4], v1[4], n1[4];
    issue_loads(R4, T4, V4, N4, b1, lane, r1, t1, v1, n1);  // prefetch

    scan_store(D_, C_, lane, b0, v0, adv4, ret4);

    phaseA(D_, C_, lane, r1, t1, n1, v1);
    scan_store(D_, C_, lane, b1, v1, adv4, ret4);
}

extern "C" void kernel_launch(void* const* d_in, const int* in_sizes, int n_in,
                              void* d_out, int out_size, void* d_ws, size_t ws_size,
                              hipStream_t stream) {
    const float* reward     = (const float*)d_in[0];
    const float* terminated = (const float*)d_in[1];
    const float* value      = (const float*)d_in[2];
    const float* next_value = (const float*)d_in[3];

    const int B = 8192;
    const int n_elem = B * 256 * 4;          // 8388608
    float* adv = (float*)d_out;
    float* ret = adv + n_elem;

    // 1024 one-shot blocks = exactly 4 blocks/CU (16 waves/CU), zero tail.
    // Each wave: 2 sequences (wv, wv+4096) with register prefetch pipeline.
    gae_scan_kernel<<<1024, 256, 0, stream>>>(reward, terminated, value,
                                              next_value, adv, ret);
}

// Round 6
// 178.194 us; speedup vs baseline: 1.0876x; 1.0876x over previous
//
#include <hip/hip_runtime.h>

// GAE: (B=8192, T=256, A=4, 1) fp32.
// g[t] = d[t] + c[t]*g[t+1], c = GAMMA*LMBDA*(1-term), g[T]=0
// adv = g, ret = g + v. d_out = [adv | ret] flat.
//
// Round-9 (half-sequence split: compact front AND 16 waves/CU):
//   Consolidated model from r1-r5: the controlling variable is the
//   instantaneous sequence-front width vs aggregate L2 (32 MB).
//     - compact 2048-seq front (r3/r4): WRITE exactly ideal 65.5 MB, 62 us
//     - 4096+-seq front (r1/r2/r5): 1.5-1.73x write amplification, 77-85 us
//   BW ledger: 2.17 TB/s @ 8 waves/CU -> 2.4-2.5 @ 16-32. XCD swizzle: null.
//   NT stores: null. To get 16 waves/CU WITHOUT widening the front, split
//   each sequence's 256-step scan across TWO waves in one block:
//     wave h=0: scan s in [0,128)   (t 255..128), produces carry g[t=128]
//     wave h=1: scan s in [128,256) (t 127..0), prefix-adjusted by carry:
//               x_tc = D_prefix + K_prefix * carry (exact composition)
//   Carry exchange: 4 floats/seq through LDS + raw s_barrier with explicit
//   lgkmcnt(0) only -- vmcnt NOT drained, so the cross-round register
//   prefetch stays in flight across the barrier.
//   1024 persistent blocks (exactly 4/CU), 4 rounds of 2048 seqs.
//
// Per-wave phases (structure verified r1-r5, halved to 128 steps):
//   A: coalesced float4 loads (thread=timestep), compute (d, cont-flag),
//      transpose-write into wave-private LDS slice (swizzled, <=2-way).
//   B: thread (tc,a) owns 8 steps; chunk composite + 4-round shuffle scan
//      + carry compose + replay.
//   C: transpose-read g, coalesced float4 stores of adv and ret=g+v.

#define GAMMA 0.99f
#define LMBDA 0.95f

typedef float f32x4 __attribute__((ext_vector_type(4)));
typedef unsigned char u8;

constexpr float K0 = GAMMA * LMBDA;

__global__ __launch_bounds__(256, 4) void gae_scan_kernel(
    const float* __restrict__ reward,
    const float* __restrict__ terminated,
    const float* __restrict__ value,
    const float* __restrict__ next_value,
    float* __restrict__ adv_out,
    float* __restrict__ ret_out)
{
    __shared__ float bufD[4][8 * 64];        // 2 KB per wave: d, then g
    __shared__ u8    bufC[4][8 * 64];        // 512 B per wave: cont flags
    __shared__ float carryBuf[2][2][4];      // [round parity][seq slot][agent]

    const int w    = threadIdx.x >> 6;       // wave id in block
    const int lane = threadIdx.x & 63;
    const int sl   = w >> 1;                 // sequence slot in block (0,1)
    const int h    = w & 1;                  // half: 0 = t[128,256), 1 = t[0,128)
    const int tb   = (1 - h) * 128;          // timestep base of this wave

    float* __restrict__ D_ = bufD[w];
    u8*    __restrict__ C_ = bufC[w];

    const f32x4* R4 = (const f32x4*)reward;
    const f32x4* T4 = (const f32x4*)terminated;
    const f32x4* V4 = (const f32x4*)value;
    const f32x4* N4 = (const f32x4*)next_value;
    f32x4* adv4 = (f32x4*)adv_out;
    f32x4* ret4 = (f32x4*)ret_out;

    const int tc = lane >> 2;                // time chunk 0..15 (8 steps each)
    const int a  = lane & 3;                 // agent channel

    const int seq0 = blockIdx.x * 2 + sl;    // seq id within a round, 0..2047

    // Double-buffered register sets for the cross-round prefetch pipeline.
    f32x4 r[2][2], tm[2][2], v[2][2], nv[2][2];

    // Prologue: loads for round 0 (2 float4 per array per lane).
#pragma unroll
    for (int q = 0; q < 2; ++q) {
        const int gi = seq0 * 256 + tb + 64 * q + lane;
        r[0][q]  = R4[gi];
        tm[0][q] = T4[gi];
        v[0][q]  = V4[gi];
        nv[0][q] = N4[gi];
    }

#pragma unroll
    for (int g = 0; g < 4; ++g) {
        const int cb = g & 1;                // compile-time after unroll
        const int nb = cb ^ 1;
        const int b  = g * 2048 + seq0;      // global sequence id

        // ---- Phase A: compute (d, flag), transpose-write to wave slice ----
#pragma unroll
        for (int q = 0; q < 2; ++q) {
            const int fl   = 64 * q + lane;  // local float4 index (= t - tb)
            const int s    = 127 - fl;       // local scan index
            const int row  = s & 7;
            const int tcq  = s >> 3;
            const int col  = (4 * tcq + 4 * row) & 63;
            const int addr = row * 64 + col; // 4-aligned

            f32x4 d4;
            d4.x = r[cb][q].x + GAMMA * nv[cb][q].x * (1.0f - tm[cb][q].x) - v[cb][q].x;
            d4.y = r[cb][q].y + GAMMA * nv[cb][q].y * (1.0f - tm[cb][q].y) - v[cb][q].y;
            d4.z = r[cb][q].z + GAMMA * nv[cb][q].z * (1.0f - tm[cb][q].z) - v[cb][q].z;
            d4.w = r[cb][q].w + GAMMA * nv[cb][q].w * (1.0f - tm[cb][q].w) - v[cb][q].w;
            const unsigned pk = (tm[cb][q].x == 0.0f ? 0x00000001u : 0u)
                              | (tm[cb][q].y == 0.0f ? 0x00000100u : 0u)
                              | (tm[cb][q].z == 0.0f ? 0x00010000u : 0u)
                              | (tm[cb][q].w == 0.0f ? 0x01000000u : 0u);
            *((f32x4*)&D_[addr])    = d4;
            *((unsigned*)&C_[addr]) = pk;
        }

        // Prefetch next round's inputs; in flight through scan + barrier.
        if (g < 3) {
#pragma unroll
            for (int q = 0; q < 2; ++q) {
                const int gi = (b + 2048) * 256 + tb + 64 * q + lane;
                r[nb][q]  = R4[gi];
                tm[nb][q] = T4[gi];
                v[nb][q]  = V4[gi];
                nv[nb][q] = N4[gi];
            }
        }

        // Wave-local: phase-A ds_writes complete before phase-B ds_reads.
        asm volatile("s_waitcnt lgkmcnt(0)" ::: "memory");

        // ---- Phase B: thread (tc,a) owns 8 steps ----
        float d[8];
        unsigned mask = 0;
#pragma unroll
        for (int j = 0; j < 8; ++j) {
            const int col = (4 * tc + 4 * j + a) & 63;
            d[j] = D_[j * 64 + col];
            mask |= ((unsigned)C_[j * 64 + col]) << j;
        }

        // Local chunk composite: out = D + K * in.
        float D = d[0];
        float K = (mask & 1u) ? K0 : 0.0f;
#pragma unroll
        for (int j = 1; j < 8; ++j) {
            const float cj = ((mask >> j) & 1u) ? K0 : 0.0f;
            D = d[j] + cj * D;
            K = cj * K;
        }

        // Inclusive shuffle scan over tc (lane stride 4): 4 steps.
#pragma unroll
        for (int s2 = 1; s2 < 16; s2 <<= 1) {
            const float pD = __shfl_up(D, (unsigned)(4 * s2), 64);
            const float pK = __shfl_up(K, (unsigned)(4 * s2), 64);
            if (tc >= s2) { D = D + K * pD; K = K * pK; }
        }

        const float Dprev = __shfl_up(D, 4u, 64);   // exclusive prefix pair
        const float Kprev = __shfl_up(K, 4u, 64);

        // Half-0 publishes its final scan state = g[t=128] for this seq.
        if (h == 0 && tc == 15) carryBuf[cb][sl][a] = D;
        asm volatile("s_waitcnt lgkmcnt(0)" ::: "memory");
        __builtin_amdgcn_sched_barrier(0);
        __builtin_amdgcn_s_barrier();            // raw: vmcnt NOT drained

        float cr = 0.0f;
        if (h == 1) cr = carryBuf[cb][sl][a];

        // State entering chunk tc: exclusive prefix applied to carry.
        // (h=0: cr=0 -> x = Dprev, matching the original init-0 scan.)
        float x;
        if (tc == 0) x = cr;
        else         x = Dprev + Kprev * cr;

        // Replay chunk, write g back into D-buffer.
        float gg = x;
#pragma unroll
        for (int j = 0; j < 8; ++j) {
            const float cj = ((mask >> j) & 1u) ? K0 : 0.0f;
            gg = d[j] + cj * gg;
            const int col = (4 * tc + 4 * j + a) & 63;
            D_[j * 64 + col] = gg;
        }
        asm volatile("s_waitcnt lgkmcnt(0)" ::: "memory");

        // ---- Phase C: transpose-read g, coalesced float4 stores ----
#pragma unroll
        for (int q = 0; q < 2; ++q) {
            const int fl  = 64 * q + lane;
            const int s   = 127 - fl;
            const int row = s & 7;
            const int tcq = s >> 3;
            const int col = (4 * tcq + 4 * row) & 63;
            const f32x4 g4 = *((const f32x4*)&D_[row * 64 + col]);

            const int gi = b * 256 + tb + fl;
            adv4[gi] = g4;
            ret4[gi] = g4 + v[cb][q];
        }
        // Keep next round's phase-A ds_writes after this phase's reads.
        asm volatile("" ::: "memory");
    }
}

extern "C" void kernel_launch(void* const* d_in, const int* in_sizes, int n_in,
                              void* d_out, int out_size, void* d_ws, size_t ws_size,
                              hipStream_t stream) {
    const float* reward     = (const float*)d_in[0];
    const float* terminated = (const float*)d_in[1];
    const float* value      = (const float*)d_in[2];
    const float* next_value = (const float*)d_in[3];

    const int B = 8192;
    const int n_elem = B * 256 * 4;          // 8388608
    float* adv = (float*)d_out;
    float* ret = adv + n_elem;

    // Persistent compact front: 1024 blocks (exactly 4/CU, 16 waves/CU).
    // Each block: 2 sequences x 2 half-waves; 4 rounds of 2048 sequences.
    gae_scan_kernel<<<1024, 256, 0, stream>>>(reward, terminated, value,
                                              next_value, adv, ret);
}

// Round 7
// 176.171 us; speedup vs baseline: 1.1001x; 1.0115x over previous
//
#include <hip/hip_runtime.h>

// GAE: (B=8192, T=256, A=4, 1) fp32.
// g[t] = d[t] + c[t]*g[t+1], c = GAMMA*LMBDA*(1-term), g[T]=0
// adv = g, ret = g + v. d_out = [adv | ret] flat.
//
// FINAL (round-7 revert to best-measured r4 variant, 60.7-63.1 us kernel):
//   Seven structures tested (r0-r6). Consolidated findings:
//   - Aggregate L2-miss service for this 6-stream pattern is pinned at
//     ~3.1 TB/s (HBM ~2.2) regardless of occupancy (8/16/32 waves/CU),
//     prefetch depth, NT stores, XCD swizzle, or wave decomposition.
//     Occupancy-doubling at fixed front width (r6 carry-split): null.
//   - FETCH_SIZE is policy-pinned at exactly half the inputs (65,600 KB
//     across three structures) - an L3 allocation equilibrium software
//     ordering cannot move.
//   - WRITE_SIZE reaches its 65,536 KB floor only with a compact
//     <=2048-sequence instantaneous front (wide fronts: 1.5-1.73x
//     write amplification through L2 thrash).
//   Ceiling arithmetic: (65.5 MB writes + 65.6 MB pinned fetch) at
//   ~2.15 TB/s => ~61 us. This kernel measures 61-64 us. Roofline.
//
// Structure: persistent compact front. 512 blocks (2/CU, 8 waves/CU),
// 2048 waves; wave w handles seqs g*2048+w, g=0..3, 2-deep register
// prefetch overlaps the scan. Device front = ~8 MB contiguous sliding
// window per array.
//
// Per-wave phases:
//   A: coalesced float4 loads (thread=timestep), compute (d, cont-flag),
//      transpose-write into wave-private LDS slice (swizzled, <=2-way).
//   B: thread (tc,a) owns 16 steps; chunk composite + 4-round shuffle scan
//      + replay. Wave-local s_waitcnt lgkmcnt(0) instead of __syncthreads.
//   C: transpose-read g, coalesced non-temporal float4 stores of adv, ret.

#define GAMMA 0.99f
#define LMBDA 0.95f

typedef float f32x4 __attribute__((ext_vector_type(4)));
typedef unsigned char u8;

constexpr float K0 = GAMMA * LMBDA;

__device__ __forceinline__ void issue_loads(
    const f32x4* __restrict__ R4, const f32x4* __restrict__ T4,
    const f32x4* __restrict__ V4, const f32x4* __restrict__ N4,
    int b, int lane, f32x4 r[4], f32x4 tm[4], f32x4 v[4], f32x4 nv[4])
{
#pragma unroll
    for (int q = 0; q < 4; ++q) {
        const int gi = b * 256 + 64 * q + lane;
        r[q]  = R4[gi];
        tm[q] = T4[gi];
        v[q]  = V4[gi];
        nv[q] = N4[gi];
    }
}

// Consume loaded regs: compute (d, cont-flag), transpose-write into LDS.
__device__ __forceinline__ void phaseA(
    float* __restrict__ D_, u8* __restrict__ C_, int lane,
    const f32x4 r[4], const f32x4 tm[4], const f32x4 nv[4], const f32x4 v[4])
{
#pragma unroll
    for (int q = 0; q < 4; ++q) {
        const int f    = 64 * q + lane;          // float4 index = timestep t
        const int s    = 255 - f;                // scan index (reversed time)
        const int row  = s & 15;
        const int col  = (4 * (s >> 4) + 4 * row) & 63;
        const int addr = row * 64 + col;         // 4-aligned

        f32x4 d4;
        d4.x = r[q].x + GAMMA * nv[q].x * (1.0f - tm[q].x) - v[q].x;
        d4.y = r[q].y + GAMMA * nv[q].y * (1.0f - tm[q].y) - v[q].y;
        d4.z = r[q].z + GAMMA * nv[q].z * (1.0f - tm[q].z) - v[q].z;
        d4.w = r[q].w + GAMMA * nv[q].w * (1.0f - tm[q].w) - v[q].w;
        const unsigned pk = (tm[q].x == 0.0f ? 0x00000001u : 0u)
                          | (tm[q].y == 0.0f ? 0x00000100u : 0u)
                          | (tm[q].z == 0.0f ? 0x00010000u : 0u)
                          | (tm[q].w == 0.0f ? 0x01000000u : 0u);
        *((f32x4*)&D_[addr])    = d4;
        *((unsigned*)&C_[addr]) = pk;
    }
}

// Wave scan over LDS slice + transposed coalesced NT stores.
__device__ __forceinline__ void scan_store(
    float* __restrict__ D_, const u8* __restrict__ C_,
    int lane, int b, const f32x4 v4[4],
    f32x4* __restrict__ adv4, f32x4* __restrict__ ret4)
{
    // Wave-local ordering: phase-A ds_writes complete before phase-B ds_reads.
    asm volatile("s_waitcnt lgkmcnt(0)" ::: "memory");

    const int tc = lane >> 2;    // time chunk 0..15
    const int a  = lane & 3;     // agent channel

    float d[16];
    unsigned mask = 0;           // bit j = continuation flag of step j
#pragma unroll
    for (int j = 0; j < 16; ++j) {
        const int col = (4 * tc + 4 * j + a) & 63;
        d[j] = D_[j * 64 + col];
        mask |= ((unsigned)C_[j * 64 + col]) << j;
    }

    // Local chunk composite: out = D + K * in.
    float D = d[0];
    float K = (mask & 1u) ? K0 : 0.0f;
#pragma unroll
    for (int j = 1; j < 16; ++j) {
        const float cj = ((mask >> j) & 1u) ? K0 : 0.0f;
        D = d[j] + cj * D;
        K = cj * K;
    }

    // Inclusive shuffle scan over tc (lane stride 4): 4 steps.
#pragma unroll
    for (int s2 = 1; s2 < 16; s2 <<= 1) {
        const float pD = __shfl_up(D, (unsigned)(4 * s2), 64);
        const float pK = __shfl_up(K, (unsigned)(4 * s2), 64);
        if (tc >= s2) { D = D + K * pD; K = K * pK; }
    }

    // Exclusive prefix = state entering this chunk.
    float x = __shfl_up(D, 4u, 64);
    if (tc == 0) x = 0.0f;

    // Replay chunk, write g back into D-buffer (d already in regs).
    float g = x;
#pragma unroll
    for (int j = 0; j < 16; ++j) {
        const float cj = ((mask >> j) & 1u) ? K0 : 0.0f;
        g = d[j] + cj * g;
        const int col = (4 * tc + 4 * j + a) & 63;
        D_[j * 64 + col] = g;
    }
    asm volatile("s_waitcnt lgkmcnt(0)" ::: "memory");

    // Transpose-read g, coalesced non-temporal float4 stores.
#pragma unroll
    for (int q = 0; q < 4; ++q) {
        const int f   = 64 * q + lane;
        const int s   = 255 - f;
        const int row = s & 15;
        const int col = (4 * (s >> 4) + 4 * row) & 63;
        const f32x4 g4 = *((const f32x4*)&D_[row * 64 + col]);

        const int gi = b * 256 + f;
        __builtin_nontemporal_store(g4, &adv4[gi]);
        const f32x4 rt = g4 + v4[q];
        __builtin_nontemporal_store(rt, &ret4[gi]);
    }
    // Keep the following phase-A ds_writes ordered after this phase's reads.
    asm volatile("" ::: "memory");
}

__global__ __launch_bounds__(256, 2) void gae_scan_kernel(
    const float* __restrict__ reward,
    const float* __restrict__ terminated,
    const float* __restrict__ value,
    const float* __restrict__ next_value,
    float* __restrict__ adv_out,
    float* __restrict__ ret_out)
{
    __shared__ float bufD[4][16 * 64];           // 16 KB: d, then reused for g
    __shared__ u8    bufC[4][16 * 64];           //  4 KB: continuation flags

    const int w    = threadIdx.x >> 6;
    const int lane = threadIdx.x & 63;
    const int wv   = blockIdx.x * 4 + w;         // global wave id, 0..2047

    float* __restrict__ D_ = bufD[w];
    u8*    __restrict__ C_ = bufC[w];

    const f32x4* R4 = (const f32x4*)reward;
    const f32x4* T4 = (const f32x4*)terminated;
    const f32x4* V4 = (const f32x4*)value;
    const f32x4* N4 = (const f32x4*)next_value;
    f32x4* adv4 = (f32x4*)adv_out;
    f32x4* ret4 = (f32x4*)ret_out;

    // Double-buffered register sets for the 2-deep prefetch pipeline.
    f32x4 r[2][4], tm[2][4], v[2][4], nv[2][4];

    issue_loads(R4, T4, V4, N4, wv, lane, r[0], tm[0], v[0], nv[0]);

#pragma unroll
    for (int g = 0; g < 4; ++g) {
        const int cb = g & 1;        // unrolled -> compile-time constant
        const int nb = cb ^ 1;
        const int b  = g * 2048 + wv;

        phaseA(D_, C_, lane, r[cb], tm[cb], nv[cb], v[cb]);

        if (g < 3) {
            // Prefetch next sequence; in flight during the scan below.
            issue_loads(R4, T4, V4, N4, b + 2048, lane,
                        r[nb], tm[nb], v[nb], nv[nb]);
        }

        scan_store(D_, C_, lane, b, v[cb], adv4, ret4);
    }
}

extern "C" void kernel_launch(void* const* d_in, const int* in_sizes, int n_in,
                              void* d_out, int out_size, void* d_ws, size_t ws_size,
                              hipStream_t stream) {
    const float* reward     = (const float*)d_in[0];
    const float* terminated = (const float*)d_in[1];
    const float* value      = (const float*)d_in[2];
    const float* next_value = (const float*)d_in[3];

    const int B = 8192;
    const int n_elem = B * 256 * 4;          // 8388608
    float* adv = (float*)d_out;
    float* ret = adv + n_elem;

    // Persistent compact front: 512 blocks (2/CU), 2048 waves, each wave
    // loops over 4 sequences at stride 2048 with 2-deep register prefetch.
    gae_scan_kernel<<<512, 256, 0, stream>>>(reward, terminated, value,
                                             next_value, adv, ret);
}